// Round 1
// baseline (194.415 us; speedup 1.0000x reference)
//
#include <hip/hip_runtime.h>
#include <hip/hip_bf16.h>
#include <stdint.h>

#define N_ROWS 16384
#define D_DIM  512
#define C_DIM  1024

typedef __attribute__((ext_vector_type(4))) float f32x4;
typedef __attribute__((ext_vector_type(8))) short bf16x8;

// f32 -> bf16 bits, round-to-nearest-even
__device__ __forceinline__ short bfbits(float x) {
  uint32_t u = __float_as_uint(x);
  uint32_t r = (u + 0x7fffu + ((u >> 16) & 1u)) >> 16;
  return (short)r;
}

__device__ __forceinline__ void gload16(const void* g, void* l) {
  __builtin_amdgcn_global_load_lds(
      (const __attribute__((address_space(1))) void*)g,
      (__attribute__((address_space(3))) void*)l, 16, 0, 0);
}

// ---- f32 rows -> bf16 rows + row sum-of-squares (exact, f32) ----
// 4 waves/block, one wave per row, 8 elems/lane (D=512)
__global__ __launch_bounds__(256) void prep_rows(const float* __restrict__ src,
                                                 short* __restrict__ dst,
                                                 float* __restrict__ sq, int nrows) {
  int row = blockIdx.x * 4 + (threadIdx.x >> 6);
  int lane = threadIdx.x & 63;
  if (row >= nrows) return;
  const float4* s = reinterpret_cast<const float4*>(src + (size_t)row * D_DIM) + lane * 2;
  float4 v0 = s[0], v1 = s[1];
  float ss = v0.x*v0.x + v0.y*v0.y + v0.z*v0.z + v0.w*v0.w
           + v1.x*v1.x + v1.y*v1.y + v1.z*v1.z + v1.w*v1.w;
  bf16x8 o;
  o[0]=bfbits(v0.x); o[1]=bfbits(v0.y); o[2]=bfbits(v0.z); o[3]=bfbits(v0.w);
  o[4]=bfbits(v1.x); o[5]=bfbits(v1.y); o[6]=bfbits(v1.z); o[7]=bfbits(v1.w);
  *reinterpret_cast<bf16x8*>(dst + (size_t)row * D_DIM + lane * 8) = o;
  #pragma unroll
  for (int off = 32; off; off >>= 1) ss += __shfl_down(ss, off, 64);
  if (lane == 0) sq[row] = ss;
}

// ---- W[c][j] f32 -> WT[j][c] bf16 bits ----
__global__ __launch_bounds__(256) void transpose_norm(const float* __restrict__ W,
                                                      short* __restrict__ WT) {
  __shared__ float tile[32][33];
  int j0 = blockIdx.x * 32;
  int c0 = blockIdx.y * 32;
  int tx = threadIdx.x & 31;
  int ty = threadIdx.x >> 5;  // 0..7
  #pragma unroll
  for (int i = 0; i < 32; i += 8)
    tile[ty + i][tx] = W[(size_t)(c0 + ty + i) * C_DIM + j0 + tx];
  __syncthreads();
  #pragma unroll
  for (int i = 0; i < 32; i += 8)
    WT[(size_t)(j0 + ty + i) * C_DIM + c0 + tx] = bfbits(tile[tx][ty + i]);
}

// ---- BT GEMM: C[M][1024] = A[M][K](bf16) x B[1024][K](bf16)^T ----
// m97 structure: 128x128 tile, BK=32, 4 waves (2x2), 4x4 16x16x32 fragments/wave.
// EPI 0: densities epilogue -> bf16   EPI 1: plain f32 store
template<int EPI>
__global__ __launch_bounds__(256)
void gemm_bt(const short* __restrict__ A, const short* __restrict__ B,
             void* __restrict__ Cp, const float* __restrict__ x2,
             const float* __restrict__ c2, const float* __restrict__ gptr,
             int K) {
  constexpr int BM = 128, BN = 128, BK = 32;
  __shared__ __align__(16) short As[BM * BK];
  __shared__ __align__(16) short Bs[BN * BK];
  const int tid  = threadIdx.x;
  const int lane = tid & 63;
  const int wid  = tid >> 6;
  const int wr = wid >> 1, wc = wid & 1;
  const int row0 = blockIdx.y * BM, col0 = blockIdx.x * BN;

  const short* Ab = A + (size_t)row0 * K;
  const short* Bb = B + (size_t)col0 * K;

  f32x4 acc[4][4] = {};

  const int ko = (lane >> 4) * 8;       // k-slice of this lane within BK
  const int rA = wr * 64 + (lane & 15); // fragment row in A tile
  const int rB = wc * 64 + (lane & 15); // fragment row in B tile (= output col)

  for (int k0 = 0; k0 < K; k0 += BK) {
    // stage A tile (8 KB) + B tile (8 KB): 2 x 16B per thread each
    #pragma unroll
    for (int i = 0; i < 2; i++) {
      int idx = i * 256 + tid;
      int r  = idx >> 2;
      int cc = (idx & 3) << 3;
      gload16(Ab + (size_t)r * K + k0 + cc, As + (size_t)(i * 256 + (tid & ~63)) * 8);
    }
    #pragma unroll
    for (int i = 0; i < 2; i++) {
      int idx = i * 256 + tid;
      int r  = idx >> 2;
      int cc = (idx & 3) << 3;
      gload16(Bb + (size_t)r * K + k0 + cc, Bs + (size_t)(i * 256 + (tid & ~63)) * 8);
    }
    __syncthreads();

    bf16x8 a[4], b[4];
    #pragma unroll
    for (int m = 0; m < 4; m++)
      a[m] = *reinterpret_cast<const bf16x8*>(&As[(rA + m * 16) * BK + ko]);
    #pragma unroll
    for (int n = 0; n < 4; n++)
      b[n] = *reinterpret_cast<const bf16x8*>(&Bs[(rB + n * 16) * BK + ko]);
    #pragma unroll
    for (int m = 0; m < 4; m++)
      #pragma unroll
      for (int n = 0; n < 4; n++)
        acc[m][n] = __builtin_amdgcn_mfma_f32_16x16x32_bf16(a[m], b[n], acc[m][n], 0, 0, 0);
    __syncthreads();
  }

  // C/D layout (m89-verified): col = lane&15, row = (lane>>4)*4 + reg
  const int colBase = col0 + wc * 64 + (lane & 15);
  const int rowBase = row0 + wr * 64 + ((lane >> 4) << 2);

  if constexpr (EPI == 0) {
    short* Dm = (short*)Cp;
    const float g = *gptr;
    float cc2[4];
    #pragma unroll
    for (int n = 0; n < 4; n++) cc2[n] = c2[colBase + n * 16];
    #pragma unroll
    for (int m = 0; m < 4; m++) {
      #pragma unroll
      for (int r = 0; r < 4; r++) {
        const int row = rowBase + m * 16 + r;
        const float xr = x2[row];
        size_t base = (size_t)row * C_DIM + colBase;
        #pragma unroll
        for (int n = 0; n < 4; n++) {
          float v = fmaxf(xr + cc2[n] - 2.0f * acc[m][n][r], 0.0f);
          Dm[base + n * 16] = bfbits(__expf(-g * v));
        }
      }
    }
  } else {
    float* Dm = (float*)Cp;
    #pragma unroll
    for (int m = 0; m < 4; m++) {
      #pragma unroll
      for (int r = 0; r < 4; r++) {
        const int row = rowBase + m * 16 + r;
        size_t base = (size_t)row * C_DIM + colBase;
        #pragma unroll
        for (int n = 0; n < 4; n++)
          Dm[base + n * 16] = acc[m][n][r];
      }
    }
  }
}

extern "C" void kernel_launch(void* const* d_in, const int* in_sizes, int n_in,
                              void* d_out, int out_size, void* d_ws, size_t ws_size,
                              hipStream_t stream) {
  const float* inputs  = (const float*)d_in[0];
  const float* centers = (const float*)d_in[1];
  const float* gamma   = (const float*)d_in[2];
  const float* norm    = (const float*)d_in[3];
  float* out = (float*)d_out;

  char* ws = (char*)d_ws;
  short* inb  = (short*)(ws);                          // 16 MiB  bf16 inputs
  short* cenb = (short*)(ws + (16u << 20));            //  1 MiB  bf16 centers
  short* wT   = (short*)(ws + (17u << 20));            //  2 MiB  bf16 norm^T
  float* x2   = (float*)(ws + (19u << 20));            // 64 KiB  ||x||^2
  float* c2   = (float*)(ws + (19u << 20) + (1u << 16)); // 4 KiB ||c||^2
  short* dens = (short*)(ws + (20u << 20));            // 32 MiB  bf16 densities

  prep_rows<<<N_ROWS / 4, 256, 0, stream>>>(inputs, inb, x2, N_ROWS);
  prep_rows<<<C_DIM / 4, 256, 0, stream>>>(centers, cenb, c2, C_DIM);
  transpose_norm<<<dim3(32, 32), 256, 0, stream>>>(norm, wT);
  gemm_bt<0><<<dim3(C_DIM / 128, N_ROWS / 128), 256, 0, stream>>>(
      inb, cenb, dens, x2, c2, gamma, D_DIM);
  gemm_bt<1><<<dim3(C_DIM / 128, N_ROWS / 128), 256, 0, stream>>>(
      dens, wT, out, nullptr, nullptr, nullptr, C_DIM);
}

// Round 5
// 151.221 us; speedup vs baseline: 1.2856x; 1.2856x over previous
//
#include <hip/hip_runtime.h>
#include <hip/hip_bf16.h>
#include <stdint.h>

#define N_ROWS 16384
#define D_DIM  512
#define C_DIM  1024

typedef __attribute__((ext_vector_type(4))) float f32x4;
typedef __attribute__((ext_vector_type(8))) short bf16x8;

// f32 -> bf16 bits, round-to-nearest-even
__device__ __forceinline__ short bfbits(float x) {
  uint32_t u = __float_as_uint(x);
  uint32_t r = (u + 0x7fffu + ((u >> 16) & 1u)) >> 16;
  return (short)r;
}

__device__ __forceinline__ void gload16(const short* g, const short* l) {
  __builtin_amdgcn_global_load_lds(
      (const __attribute__((address_space(1))) void*)g,
      (__attribute__((address_space(3))) void*)l, 16, 0, 0);
}

// ---- fused prep: inputs->bf16+|x|^2, centers->bf16+|c|^2, W -> W^T bf16 ----
__global__ __launch_bounds__(256) void fused_prep(
    const float* __restrict__ inputs, const float* __restrict__ centers,
    const float* __restrict__ W, short* __restrict__ inb,
    short* __restrict__ cenb, short* __restrict__ wT,
    float* __restrict__ x2, float* __restrict__ c2) {
  int bid = blockIdx.x;
  if (bid < 4096 + 256) {
    // row prep: 4 waves/block, one wave per row of 512 floats
    const float* src; short* dst; float* sq; int row;
    if (bid < 4096) { src = inputs; dst = inb; sq = x2; row = bid * 4 + (threadIdx.x >> 6); }
    else { src = centers; dst = cenb; sq = c2; row = (bid - 4096) * 4 + (threadIdx.x >> 6); }
    int lane = threadIdx.x & 63;
    const float4* s = reinterpret_cast<const float4*>(src + (size_t)row * D_DIM) + lane * 2;
    float4 v0 = s[0], v1 = s[1];
    float ss = v0.x*v0.x + v0.y*v0.y + v0.z*v0.z + v0.w*v0.w
             + v1.x*v1.x + v1.y*v1.y + v1.z*v1.z + v1.w*v1.w;
    bf16x8 o;
    o[0]=bfbits(v0.x); o[1]=bfbits(v0.y); o[2]=bfbits(v0.z); o[3]=bfbits(v0.w);
    o[4]=bfbits(v1.x); o[5]=bfbits(v1.y); o[6]=bfbits(v1.z); o[7]=bfbits(v1.w);
    *reinterpret_cast<bf16x8*>(dst + (size_t)row * D_DIM + lane * 8) = o;
    #pragma unroll
    for (int off = 32; off; off >>= 1) ss += __shfl_down(ss, off, 64);
    if (lane == 0) sq[row] = ss;
  } else {
    // transpose W[c][j] -> wT[j][c] (bf16)
    __shared__ float tile[32][33];
    int b2 = bid - 4352;
    int j0 = (b2 & 31) * 32;
    int c0 = (b2 >> 5) * 32;
    int tx = threadIdx.x & 31;
    int ty = threadIdx.x >> 5;  // 0..7
    #pragma unroll
    for (int i = 0; i < 32; i += 8)
      tile[ty + i][tx] = W[(size_t)(c0 + ty + i) * C_DIM + j0 + tx];
    __syncthreads();
    #pragma unroll
    for (int i = 0; i < 32; i += 8)
      wT[(size_t)(j0 + ty + i) * C_DIM + c0 + tx] = bfbits(tile[tx][ty + i]);
  }
}

// ---- 256x256 8-phase BT GEMM: C[M][1024] = A[M][K] x B[1024][K]^T (bf16 in) ----
// 8 waves (2Mx4N), BK=64, dbuf LDS 128KB, st-swizzle c^((r&7)<<3), counted vmcnt.
// EPI 0: RBF densities epilogue -> bf16    EPI 1: plain f32 store
template<int EPI>
__global__ __launch_bounds__(512, 2)
void gemm256(const short* __restrict__ A, const short* __restrict__ B,
             void* __restrict__ Cp, const float* __restrict__ x2,
             const float* __restrict__ c2, const float* __restrict__ gptr,
             int K) {
  __shared__ __align__(16) short lds[65536];  // A: [0,32768)  B: [32768,65536)
  short* As = lds;
  short* Bs = lds + 32768;

  const int tid  = threadIdx.x;
  const int lane = tid & 63;
  const int wid  = tid >> 6;
  const int wr = wid >> 2;   // 0..1
  const int wc = wid & 3;    // 0..3

  // XCD-aware bijective swizzle: 64 row-blocks x 4 col-blocks, 256 blocks.
  // XCD k (= bid&7) owns row-panels [k*8, k*8+8) x all 4 col-blocks.
  const int bid  = blockIdx.x;
  const int brow = (bid & 7) * 8 + (bid >> 5);
  const int bcol = (bid >> 3) & 3;
  const int row0 = brow * 256, col0 = bcol * 256;

  const int NT = K >> 6;

  // fragment ds_read addressing (swizzled): elem (r,c) stored at c^((r&7)<<3)
  const int l15 = lane & 15;
  const int lk  = (lane >> 4) * 8;
  const int sw  = (lane & 7) << 3;
  const int swHi = sw & 32, swLo = sw & 24;
  const int ca0 = swHi | (lk ^ swLo);          // kk=0 swizzled col (shorts)
  const int ca1 = (swHi ^ 32) | (lk ^ swLo);   // kk=1
  const int aRow = (wr * 128 + l15) * 64;
  const int bRow = (wc * 64  + l15) * 64;

  // staging addressing: unit = 64 rows x 64 shorts = 8KB = 512 threads x 16B
  const int rowL = tid >> 3;                        // 0..63
  const int chS  = ((tid & 7) ^ (rowL & 7)) << 3;   // pre-swizzled source chunk
  const short* gA = A + (size_t)(row0 + rowL) * K + chS;
  const short* gB = B + (size_t)(col0 + rowL) * K + chS;
  const int ldsT = tid * 8;

#define STG_A(buf, u, kt) gload16(gA + (size_t)((u) * 64) * K + (kt), As + (buf) * 16384 + (u) * 4096 + ldsT)
#define STG_B(buf, u, kt) gload16(gB + (size_t)((u) * 64) * K + (kt), Bs + (buf) * 16384 + (u) * 4096 + ldsT)

  f32x4 acc[8][4] = {};

  // prologue: tile0 -> buf0 (B u0-3, A u0,u2,u1,u3), then B(1) u0,u1 -> buf1
  STG_B(0, 0, 0); STG_B(0, 1, 0); STG_B(0, 2, 0); STG_B(0, 3, 0);
  STG_A(0, 0, 0); STG_A(0, 2, 0); STG_A(0, 1, 0); STG_A(0, 3, 0);
  {
    const int kt1 = (NT > 1) ? 64 : 0;
    STG_B(1, 0, kt1); STG_B(1, 1, kt1);
  }
  asm volatile("s_waitcnt vmcnt(4)" ::: "memory");  // B0 + A0(u0,u2) resident
  __builtin_amdgcn_s_barrier();

  bf16x8 a[4], b0[4], b1[4];
  for (int t = 0; t < NT; ++t) {
    const int bsel = t & 1, nb = bsel ^ 1;
    const short* aB = As + bsel * 16384;
    const short* bB = Bs + bsel * 16384;
    const int ktS1 = ((t + 1 < NT) ? (t + 1) : (NT - 1)) << 6;
    const int ktS2 = ((t + 2 < NT) ? (t + 2) : (NT - 1)) << 6;

    // ---- P1: a(m0-3,kk0) + b(kk0); stage B(t+1) u2,u3 ----
    #pragma unroll
    for (int i = 0; i < 4; ++i) a[i]  = *(const bf16x8*)(aB + aRow + i * 1024 + ca0);
    #pragma unroll
    for (int n = 0; n < 4; ++n) b0[n] = *(const bf16x8*)(bB + bRow + n * 1024 + ca0);
    STG_B(nb, 2, ktS1); STG_B(nb, 3, ktS1);
    __builtin_amdgcn_s_barrier();
    asm volatile("s_waitcnt lgkmcnt(0)" ::: "memory");
    __builtin_amdgcn_sched_barrier(0);
    __builtin_amdgcn_s_setprio(1);
    #pragma unroll
    for (int i = 0; i < 4; ++i)
      #pragma unroll
      for (int n = 0; n < 4; ++n)
        acc[i][n] = __builtin_amdgcn_mfma_f32_16x16x32_bf16(a[i], b0[n], acc[i][n], 0, 0, 0);
    __builtin_amdgcn_s_setprio(0);
    asm volatile("s_waitcnt vmcnt(4)" ::: "memory");  // A(t) u1,u3 resident for P2
    __builtin_amdgcn_s_barrier();

    // ---- P2: a(m4-7,kk0); stage A(t+1) u0,u2 ----
    #pragma unroll
    for (int i = 0; i < 4; ++i) a[i] = *(const bf16x8*)(aB + aRow + (4 + i) * 1024 + ca0);
    STG_A(nb, 0, ktS1); STG_A(nb, 2, ktS1);
    __builtin_amdgcn_s_barrier();
    asm volatile("s_waitcnt lgkmcnt(0)" ::: "memory");
    __builtin_amdgcn_sched_barrier(0);
    __builtin_amdgcn_s_setprio(1);
    #pragma unroll
    for (int i = 0; i < 4; ++i)
      #pragma unroll
      for (int n = 0; n < 4; ++n)
        acc[4 + i][n] = __builtin_amdgcn_mfma_f32_16x16x32_bf16(a[i], b0[n], acc[4 + i][n], 0, 0, 0);
    __builtin_amdgcn_s_setprio(0);
    __builtin_amdgcn_s_barrier();

    // ---- P3: a(m0-3,kk1) + b(kk1); stage A(t+1) u1,u3 ----
    #pragma unroll
    for (int i = 0; i < 4; ++i) a[i]  = *(const bf16x8*)(aB + aRow + i * 1024 + ca1);
    #pragma unroll
    for (int n = 0; n < 4; ++n) b1[n] = *(const bf16x8*)(bB + bRow + n * 1024 + ca1);
    STG_A(nb, 1, ktS1); STG_A(nb, 3, ktS1);
    __builtin_amdgcn_s_barrier();
    asm volatile("s_waitcnt lgkmcnt(0)" ::: "memory");
    __builtin_amdgcn_sched_barrier(0);
    __builtin_amdgcn_s_setprio(1);
    #pragma unroll
    for (int i = 0; i < 4; ++i)
      #pragma unroll
      for (int n = 0; n < 4; ++n)
        acc[i][n] = __builtin_amdgcn_mfma_f32_16x16x32_bf16(a[i], b1[n], acc[i][n], 0, 0, 0);
    __builtin_amdgcn_s_setprio(0);
    __builtin_amdgcn_s_barrier();

    // ---- P4: a(m4-7,kk1); stage B(t+2) u0,u1 into current buf (B region free) ----
    #pragma unroll
    for (int i = 0; i < 4; ++i) a[i] = *(const bf16x8*)(aB + aRow + (4 + i) * 1024 + ca1);
    STG_B(bsel, 0, ktS2); STG_B(bsel, 1, ktS2);
    __builtin_amdgcn_s_barrier();
    asm volatile("s_waitcnt lgkmcnt(0)" ::: "memory");
    __builtin_amdgcn_sched_barrier(0);
    __builtin_amdgcn_s_setprio(1);
    #pragma unroll
    for (int i = 0; i < 4; ++i)
      #pragma unroll
      for (int n = 0; n < 4; ++n)
        acc[4 + i][n] = __builtin_amdgcn_mfma_f32_16x16x32_bf16(a[i], b1[n], acc[4 + i][n], 0, 0, 0);
    __builtin_amdgcn_s_setprio(0);
    asm volatile("s_waitcnt vmcnt(4)" ::: "memory");  // A(t+1) u0,u2 + B(t+1) resident for P1
    __builtin_amdgcn_s_barrier();
  }

  // epilogue. C/D layout: col = lane&15 (B side), row = (lane>>4)*4 + reg (A side)
  const int colB = col0 + wc * 64 + l15;
  const int rBase = row0 + wr * 128 + ((lane >> 4) << 2);

  if constexpr (EPI == 0) {
    short* Dm = (short*)Cp;
    const float g = *gptr;
    float cc2[4];
    #pragma unroll
    for (int n = 0; n < 4; ++n) cc2[n] = c2[colB + n * 16];
    #pragma unroll
    for (int m = 0; m < 8; ++m) {
      #pragma unroll
      for (int r = 0; r < 4; ++r) {
        const int row = rBase + m * 16 + r;
        const float xr = x2[row];
        size_t base = (size_t)row * C_DIM + colB;
        #pragma unroll
        for (int n = 0; n < 4; ++n) {
          float v = fmaxf(xr + cc2[n] - 2.0f * acc[m][n][r], 0.0f);
          Dm[base + n * 16] = bfbits(__expf(-g * v));
        }
      }
    }
  } else {
    float* Dm = (float*)Cp;
    #pragma unroll
    for (int m = 0; m < 8; ++m) {
      #pragma unroll
      for (int r = 0; r < 4; ++r) {
        const int row = rBase + m * 16 + r;
        size_t base = (size_t)row * C_DIM + colB;
        #pragma unroll
        for (int n = 0; n < 4; ++n)
          Dm[base + n * 16] = acc[m][n][r];
      }
    }
  }
#undef STG_A
#undef STG_B
}

extern "C" void kernel_launch(void* const* d_in, const int* in_sizes, int n_in,
                              void* d_out, int out_size, void* d_ws, size_t ws_size,
                              hipStream_t stream) {
  const float* inputs  = (const float*)d_in[0];
  const float* centers = (const float*)d_in[1];
  const float* gamma   = (const float*)d_in[2];
  const float* norm    = (const float*)d_in[3];
  float* out = (float*)d_out;

  char* ws = (char*)d_ws;
  short* inb  = (short*)(ws);                            // 16 MiB  bf16 inputs
  short* cenb = (short*)(ws + (16u << 20));              //  1 MiB  bf16 centers
  short* wT   = (short*)(ws + (17u << 20));              //  2 MiB  bf16 norm^T
  float* x2   = (float*)(ws + (19u << 20));              // 64 KiB  ||x||^2
  float* c2   = (float*)(ws + (19u << 20) + (1u << 16)); //  4 KiB  ||c||^2
  short* dens = (short*)(ws + (20u << 20));              // 32 MiB  bf16 densities

  fused_prep<<<5376, 256, 0, stream>>>(inputs, centers, norm, inb, cenb, wT, x2, c2);
  gemm256<0><<<256, 512, 0, stream>>>(inb, cenb, dens, x2, c2, gamma, D_DIM);
  gemm256<1><<<256, 512, 0, stream>>>(dens, wT, out, nullptr, nullptr, nullptr, C_DIM);
}